// Round 1
// baseline (993.088 us; speedup 1.0000x reference)
//
#include <hip/hip_runtime.h>

#define NN 100000
#define NE 1600000
#define HD 128
#define NG 128
#define NC 10
#define EPSV 1e-5f

// ---------------- preprocessing: degree, prefix-scan, dst-sorted edges ----------------

__global__ __launch_bounds__(256) void k_count(const int* __restrict__ ei, int* __restrict__ counts){
  int e = blockIdx.x*256 + threadIdx.x;
  if(e < NE) atomicAdd(&counts[ei[NE + e]], 1);
}

__global__ __launch_bounds__(256) void k_scan1(const int* __restrict__ cnts, int* __restrict__ rowstart,
                                               int* __restrict__ bsums){
  __shared__ int lds[256];
  int b = blockIdx.x, t = threadIdx.x;
  int base = b*1024 + t*4;
  int v0 = (base+0 < NN) ? cnts[base+0] : 0;
  int v1 = (base+1 < NN) ? cnts[base+1] : 0;
  int v2 = (base+2 < NN) ? cnts[base+2] : 0;
  int v3 = (base+3 < NN) ? cnts[base+3] : 0;
  int s1 = v0+v1, s2 = s1+v2, s3 = s2+v3;
  lds[t] = s3;
  __syncthreads();
  for(int off=1; off<256; off<<=1){
    int y = lds[t];
    int z = (t>=off) ? lds[t-off] : 0;
    __syncthreads();
    lds[t] = y+z;
    __syncthreads();
  }
  int excl = (t>0) ? lds[t-1] : 0;
  if(base+0 < NN) rowstart[base+1] = excl + v0;
  if(base+1 < NN) rowstart[base+2] = excl + s1;
  if(base+2 < NN) rowstart[base+3] = excl + s2;
  if(base+3 < NN) rowstart[base+4] = excl + s3;
  if(t == 255) bsums[b] = lds[255];
}

__global__ void k_scan2(int* __restrict__ bsums, int nb){
  __shared__ int lds[256];
  int t = threadIdx.x;
  int v = (t < nb) ? bsums[t] : 0;
  lds[t] = v;
  __syncthreads();
  for(int off=1; off<256; off<<=1){
    int y = lds[t];
    int z = (t>=off) ? lds[t-off] : 0;
    __syncthreads();
    lds[t] = y+z;
    __syncthreads();
  }
  int excl = (t>0) ? lds[t-1] : 0;
  if(t < nb) bsums[t] = excl;
}

__global__ __launch_bounds__(256) void k_scan3(int* __restrict__ rowstart, const int* __restrict__ bsums){
  int b = blockIdx.x, t = threadIdx.x;
  int add = bsums[b];
  int base = b*1024 + t*4;
  #pragma unroll
  for(int j=0;j<4;j++)
    if(base+j < NN) rowstart[base+j+1] += add;
  if(b==0 && t==0) rowstart[0] = 0;
}

__global__ __launch_bounds__(256) void k_dinv(const int* __restrict__ counts, float* __restrict__ dinv){
  int n = blockIdx.x*256 + threadIdx.x;
  if(n < NN) dinv[n] = rsqrtf((float)(counts[n] + 1));  // deg = indeg + self loop
}

__global__ __launch_bounds__(256) void k_scatter(const int* __restrict__ ei, const int* __restrict__ rowstart,
                                                 int* __restrict__ cursor, int* __restrict__ srcs){
  int e = blockIdx.x*256 + threadIdx.x;
  if(e < NE){
    int d = ei[NE + e];
    int pos = rowstart[d] + atomicAdd(&cursor[d], 1);
    srcs[pos] = ei[e];
  }
}

// batch is sorted -> contiguous per-graph node ranges
__global__ __launch_bounds__(256) void k_granges(const int* __restrict__ batch, int* __restrict__ gstart){
  int n = blockIdx.x*256 + threadIdx.x;
  if(n >= NN) return;
  int b = batch[n];
  if(n == 0){
    for(int g=0; g<=b; g++) gstart[g] = 0;
    int last = batch[NN-1];
    for(int g=last+1; g<=NG; g++) gstart[g] = NN;
  } else {
    int bp = batch[n-1];
    for(int g=bp+1; g<=b; g++) gstart[g] = n;
  }
}

// ---------------- GEMM: out = dinv[row] * (norm_relu(in) @ w), 128x128 tile ----------------
// NORM=0: raw input (layer 1). NORM=1: fused GraphNorm+ReLU on load using am/rs tables.
template<int NORM>
__global__ __launch_bounds__(256, 2)
void k_gemm(const float* __restrict__ in, const float* __restrict__ w,
            float* __restrict__ outg, const float* __restrict__ dinv,
            const int* __restrict__ batch,
            const float* __restrict__ gw, const float* __restrict__ gb,
            const float* __restrict__ am_tab, const float* __restrict__ rs_tab)
{
  extern __shared__ float xk[];   // [128 rows][128 k], 64 KiB -> 2 blocks/CU
  const int t = threadIdx.x;
  const int row0 = blockIdx.x * 128;
  {
    const int l = t & 31;         // float4 index within a row (f0 = 4*l)
    const int rr = t >> 5;        // 0..7
    float4 gwv, gbv;
    if(NORM){ gwv = ((const float4*)gw)[l]; gbv = ((const float4*)gb)[l]; }
    #pragma unroll 4
    for(int rb = 0; rb < 16; rb++){
      int r = rb*8 + rr;
      int node = row0 + r;
      float4 v = make_float4(0.f,0.f,0.f,0.f);
      if(node < NN){
        v = ((const float4*)in)[(size_t)node*32 + l];
        if(NORM){
          int g = batch[node];
          float4 am = ((const float4*)am_tab)[g*32 + l];
          float4 rs = ((const float4*)rs_tab)[g*32 + l];
          v.x = fmaxf(gwv.x*(v.x-am.x)*rs.x + gbv.x, 0.f);
          v.y = fmaxf(gwv.y*(v.y-am.y)*rs.y + gbv.y, 0.f);
          v.z = fmaxf(gwv.z*(v.z-am.z)*rs.z + gbv.z, 0.f);
          v.w = fmaxf(gwv.w*(v.w-am.w)*rs.w + gbv.w, 0.f);
        }
      }
      *(float4*)(xk + r*128 + l*4) = v;
    }
  }
  __syncthreads();

  const int tc = t & 15, tr = t >> 4;
  const int r0 = tr*8, c0 = tc*8;
  float acc[8][8];
  #pragma unroll
  for(int i=0;i<8;i++)
    #pragma unroll
    for(int j=0;j<8;j++) acc[i][j] = 0.f;

  #pragma unroll 2
  for(int k=0; k<128; k+=4){
    float4 xa[8];
    #pragma unroll
    for(int i=0;i<8;i++) xa[i] = *(const float4*)(xk + (r0+i)*128 + k);
    #pragma unroll
    for(int kk=0; kk<4; kk++){
      float4 w0 = *(const float4*)(w + (k+kk)*128 + c0);
      float4 w1 = *(const float4*)(w + (k+kk)*128 + c0 + 4);
      float wcol[8] = {w0.x,w0.y,w0.z,w0.w,w1.x,w1.y,w1.z,w1.w};
      #pragma unroll
      for(int i=0;i<8;i++){
        float xv = (kk==0)?xa[i].x:(kk==1)?xa[i].y:(kk==2)?xa[i].z:xa[i].w;
        #pragma unroll
        for(int j=0;j<8;j++) acc[i][j] = fmaf(xv, wcol[j], acc[i][j]);
      }
    }
  }

  #pragma unroll
  for(int i=0;i<8;i++){
    int node = row0 + r0 + i;
    if(node < NN){
      float dv = dinv[node];
      float4 o0 = make_float4(acc[i][0]*dv, acc[i][1]*dv, acc[i][2]*dv, acc[i][3]*dv);
      float4 o1 = make_float4(acc[i][4]*dv, acc[i][5]*dv, acc[i][6]*dv, acc[i][7]*dv);
      float* op = outg + (size_t)node*128 + c0;
      *(float4*)op = o0;
      *(float4*)(op+4) = o1;
    }
  }
}

// ---------------- aggregation over dst-sorted edges: out[n] = dinv[n]*(sum g[src] + g[n]) + b ----
__global__ __launch_bounds__(256)
void k_agg(const float* __restrict__ g, const int* __restrict__ rowstart,
           const int* __restrict__ srcs, const float* __restrict__ dinv,
           const float* __restrict__ bias, float* __restrict__ outp)
{
  int lane = threadIdx.x & 31;                // float4 slot: 32 lanes * 4 floats = 128
  int node = blockIdx.x*8 + (threadIdx.x >> 5);
  if(node >= NN) return;
  int e0 = rowstart[node], e1 = rowstart[node+1];
  float4 acc = make_float4(0.f,0.f,0.f,0.f);
  const float4* gp = (const float4*)g;
  int e = e0;
  for(; e+1 < e1; e += 2){
    int s0 = srcs[e], s1 = srcs[e+1];
    float4 va = gp[(size_t)s0*32 + lane];
    float4 vb = gp[(size_t)s1*32 + lane];
    acc.x += va.x + vb.x; acc.y += va.y + vb.y;
    acc.z += va.z + vb.z; acc.w += va.w + vb.w;
  }
  if(e < e1){
    int s0 = srcs[e];
    float4 va = gp[(size_t)s0*32 + lane];
    acc.x += va.x; acc.y += va.y; acc.z += va.z; acc.w += va.w;
  }
  float4 self = gp[(size_t)node*32 + lane];
  float dv = dinv[node];
  float4 bv = ((const float4*)bias)[lane];
  float4 o = make_float4(dv*(acc.x+self.x)+bv.x, dv*(acc.y+self.y)+bv.y,
                         dv*(acc.z+self.z)+bv.z, dv*(acc.w+self.w)+bv.w);
  ((float4*)outp)[(size_t)node*32 + lane] = o;
}

// ---------------- per-graph moments (one pass: sum x, sum x^2) ----------------
#define STAT_CH 8
__global__ __launch_bounds__(128)
void k_stats(const float* __restrict__ x, const int* __restrict__ gstart,
             float* __restrict__ S1, float* __restrict__ S2)
{
  int g = blockIdx.x, ch = blockIdx.y, f = threadIdx.x;
  int s = gstart[g], e = gstart[g+1];
  int len = e - s;
  int i0 = s + (int)((long long)len * ch / STAT_CH);
  int i1 = s + (int)((long long)len * (ch+1) / STAT_CH);
  float a1 = 0.f, a2 = 0.f;
  for(int n=i0; n<i1; n++){
    float v = x[(size_t)n*128 + f];
    a1 += v; a2 += v*v;
  }
  if(i1 > i0){
    atomicAdd(&S1[g*128+f], a1);
    atomicAdd(&S2[g*128+f], a2);
  }
}

// var = E[x^2] - (2a - a^2) m^2 ;  tables: am = a*m, rs = rsqrt(var+eps)
__global__ __launch_bounds__(256)
void k_finalize(const float* __restrict__ S1, const float* __restrict__ S2,
                const int* __restrict__ gstart, const float* __restrict__ ga,
                float* __restrict__ am_tab, float* __restrict__ rs_tab)
{
  int i = blockIdx.x*256 + threadIdx.x;
  if(i >= NG*HD) return;
  int g = i >> 7, f = i & 127;
  int len = gstart[g+1] - gstart[g];
  float cnt = (float)(len > 0 ? len : 1);
  float inv = 1.f/cnt;
  float m = S1[i]*inv, ex2 = S2[i]*inv;
  float a = ga[f];
  float var = ex2 - (2.f*a - a*a)*m*m;
  am_tab[i] = a*m;
  rs_tab[i] = rsqrtf(var + EPSV);
}

// ---------------- pooled[g][f] = sum_n relu(norm3(x[n][f]))  (divide by cnt in head) ----------
__global__ __launch_bounds__(128)
void k_pool(const float* __restrict__ x, const int* __restrict__ gstart,
            const float* __restrict__ gw, const float* __restrict__ gb,
            const float* __restrict__ am_tab, const float* __restrict__ rs_tab,
            float* __restrict__ pooled)
{
  int g = blockIdx.x, ch = blockIdx.y, f = threadIdx.x;
  int s = gstart[g], e = gstart[g+1];
  int len = e - s;
  int i0 = s + (int)((long long)len * ch / STAT_CH);
  int i1 = s + (int)((long long)len * (ch+1) / STAT_CH);
  float wv = gw[f], bv = gb[f];
  float am = am_tab[g*128+f], rs = rs_tab[g*128+f];
  float a1 = 0.f;
  for(int n=i0; n<i1; n++){
    float v = x[(size_t)n*128 + f];
    v = wv*(v-am)*rs + bv;
    a1 += fmaxf(v, 0.f);
  }
  if(i1 > i0) atomicAdd(&pooled[g*128+f], a1);
}

// ---------------- head: logits = pooled/cnt @ lw + lb, log_softmax ----------------
__global__ __launch_bounds__(64)
void k_head(const float* __restrict__ pooled, const int* __restrict__ gstart,
            const float* __restrict__ lw, const float* __restrict__ lb,
            float* __restrict__ out)
{
  int g = blockIdx.x, t = threadIdx.x;
  __shared__ float lg[NC];
  __shared__ float lse_s;
  int len = gstart[g+1] - gstart[g];
  float inv = 1.f/(float)(len > 0 ? len : 1);
  if(t < NC){
    float acc = lb[t];
    for(int f=0; f<128; f++) acc += pooled[g*128+f]*inv*lw[f*NC + t];
    lg[t] = acc;
  }
  __syncthreads();
  if(t == 0){
    float mx = -1e30f;
    for(int c=0;c<NC;c++) mx = fmaxf(mx, lg[c]);
    float sm = 0.f;
    for(int c=0;c<NC;c++) sm += expf(lg[c]-mx);
    lse_s = mx + logf(sm);
  }
  __syncthreads();
  if(t < NC) out[g*NC + t] = lg[t] - lse_s;
}

// ---------------- launch ----------------
extern "C" void kernel_launch(void* const* d_in, const int* in_sizes, int n_in,
                              void* d_out, int out_size, void* d_ws, size_t ws_size,
                              hipStream_t stream)
{
  const float* x    = (const float*)d_in[0];
  const int*   ei   = (const int*)d_in[1];
  const int*   batch= (const int*)d_in[2];
  const float* w1   = (const float*)d_in[3];
  const float* b1   = (const float*)d_in[4];
  const float* w2   = (const float*)d_in[5];
  const float* b2   = (const float*)d_in[6];
  const float* w3   = (const float*)d_in[7];
  const float* b3   = (const float*)d_in[8];
  const float* g1w  = (const float*)d_in[9];
  const float* g1b  = (const float*)d_in[10];
  const float* g1a  = (const float*)d_in[11];
  const float* g2w  = (const float*)d_in[12];
  const float* g2b  = (const float*)d_in[13];
  const float* g2a  = (const float*)d_in[14];
  const float* g3w  = (const float*)d_in[15];
  const float* g3b  = (const float*)d_in[16];
  const float* g3a  = (const float*)d_in[17];
  const float* lw   = (const float*)d_in[18];
  const float* lb   = (const float*)d_in[19];
  float* out = (float*)d_out;

  char* p = (char*)d_ws;
  auto take = [&](size_t nbytes){ char* q = p; p += (nbytes + 255) & ~(size_t)255; return q; };
  float* bufA     = (float*)take((size_t)NN*HD*4);
  float* bufB     = (float*)take((size_t)NN*HD*4);
  int*   counts   = (int*)  take((size_t)NN*4);
  int*   rowstart = (int*)  take((size_t)(NN+1)*4);
  int*   cursor   = (int*)  take((size_t)NN*4);
  int*   srcs     = (int*)  take((size_t)NE*4);
  float* dinv     = (float*)take((size_t)NN*4);
  int*   gstart   = (int*)  take((size_t)(NG+1)*4);
  float* S1       = (float*)take((size_t)NG*HD*4);
  float* S2       = (float*)take((size_t)NG*HD*4);
  float* am_tab   = (float*)take((size_t)NG*HD*4);
  float* rs_tab   = (float*)take((size_t)NG*HD*4);
  float* pooled   = (float*)take((size_t)NG*HD*4);
  int*   bsums    = (int*)  take((size_t)512*4);
  if((size_t)(p - (char*)d_ws) > ws_size) return;  // workspace too small: fail visibly

  hipMemsetAsync(counts, 0, (size_t)NN*4, stream);
  hipMemsetAsync(cursor, 0, (size_t)NN*4, stream);

  const int NB = (NN + 1023)/1024;   // 98
  k_count  <<<(NE+255)/256, 256, 0, stream>>>(ei, counts);
  k_scan1  <<<NB, 256, 0, stream>>>(counts, rowstart, bsums);
  k_scan2  <<<1, 256, 0, stream>>>(bsums, NB);
  k_scan3  <<<NB, 256, 0, stream>>>(rowstart, bsums);
  k_dinv   <<<(NN+255)/256, 256, 0, stream>>>(counts, dinv);
  k_scatter<<<(NE+255)/256, 256, 0, stream>>>(ei, rowstart, cursor, srcs);
  k_granges<<<(NN+255)/256, 256, 0, stream>>>(batch, gstart);

  const int GB = (NN + 127)/128;     // 782
  const size_t LDSZ = 128*128*4;     // 64 KiB

  // ---- layer 1 ----
  k_gemm<0><<<GB, 256, LDSZ, stream>>>(x, w1, bufA, dinv, batch, nullptr, nullptr, nullptr, nullptr);
  k_agg<<<(NN+7)/8, 256, 0, stream>>>(bufA, rowstart, srcs, dinv, b1, bufB);
  hipMemsetAsync(S1, 0, (size_t)NG*HD*4, stream);
  hipMemsetAsync(S2, 0, (size_t)NG*HD*4, stream);
  k_stats<<<dim3(NG, STAT_CH), 128, 0, stream>>>(bufB, gstart, S1, S2);
  k_finalize<<<(NG*HD+255)/256, 256, 0, stream>>>(S1, S2, gstart, g1a, am_tab, rs_tab);

  // ---- layer 2 ----
  k_gemm<1><<<GB, 256, LDSZ, stream>>>(bufB, w2, bufA, dinv, batch, g1w, g1b, am_tab, rs_tab);
  k_agg<<<(NN+7)/8, 256, 0, stream>>>(bufA, rowstart, srcs, dinv, b2, bufB);
  hipMemsetAsync(S1, 0, (size_t)NG*HD*4, stream);
  hipMemsetAsync(S2, 0, (size_t)NG*HD*4, stream);
  k_stats<<<dim3(NG, STAT_CH), 128, 0, stream>>>(bufB, gstart, S1, S2);
  k_finalize<<<(NG*HD+255)/256, 256, 0, stream>>>(S1, S2, gstart, g2a, am_tab, rs_tab);

  // ---- layer 3 ----
  k_gemm<1><<<GB, 256, LDSZ, stream>>>(bufB, w3, bufA, dinv, batch, g2w, g2b, am_tab, rs_tab);
  k_agg<<<(NN+7)/8, 256, 0, stream>>>(bufA, rowstart, srcs, dinv, b3, bufB);
  hipMemsetAsync(S1, 0, (size_t)NG*HD*4, stream);
  hipMemsetAsync(S2, 0, (size_t)NG*HD*4, stream);
  k_stats<<<dim3(NG, STAT_CH), 128, 0, stream>>>(bufB, gstart, S1, S2);
  k_finalize<<<(NG*HD+255)/256, 256, 0, stream>>>(S1, S2, gstart, g3a, am_tab, rs_tab);

  // ---- pool + head ----
  hipMemsetAsync(pooled, 0, (size_t)NG*HD*4, stream);
  k_pool<<<dim3(NG, STAT_CH), 128, 0, stream>>>(bufB, gstart, g3w, g3b, am_tab, rs_tab, pooled);
  k_head<<<NG, 64, 0, stream>>>(pooled, gstart, lw, lb, out);
}

// Round 2
// 675.886 us; speedup vs baseline: 1.4693x; 1.4693x over previous
//
#include <hip/hip_runtime.h>

#define NN 100000
#define NE 1600000
#define HD 128
#define NG 128
#define NC 10
#define EPSV 1e-5f

typedef __attribute__((ext_vector_type(8))) short short8;
typedef __attribute__((ext_vector_type(4))) float f32x4;

__device__ __forceinline__ float b2f(ushort u){ return __uint_as_float(((unsigned)u)<<16); }
__device__ __forceinline__ ushort f2b(float f){
  unsigned u = __float_as_uint(f);
  unsigned r = (u + 0x7FFFu + ((u>>16)&1u)) >> 16;   // RNE, no NaN handling (inputs sane)
  return (ushort)r;
}

// ---------------- preprocessing: degree, prefix-scan, dst-sorted edges ----------------

__global__ __launch_bounds__(256) void k_count(const int* __restrict__ ei, int* __restrict__ counts){
  int e = blockIdx.x*256 + threadIdx.x;
  if(e < NE) atomicAdd(&counts[ei[NE + e]], 1);
}

__global__ __launch_bounds__(256) void k_scan1(const int* __restrict__ cnts, int* __restrict__ rowstart,
                                               int* __restrict__ bsums){
  __shared__ int lds[256];
  int b = blockIdx.x, t = threadIdx.x;
  int base = b*1024 + t*4;
  int v0 = (base+0 < NN) ? cnts[base+0] : 0;
  int v1 = (base+1 < NN) ? cnts[base+1] : 0;
  int v2 = (base+2 < NN) ? cnts[base+2] : 0;
  int v3 = (base+3 < NN) ? cnts[base+3] : 0;
  int s1 = v0+v1, s2 = s1+v2, s3 = s2+v3;
  lds[t] = s3;
  __syncthreads();
  for(int off=1; off<256; off<<=1){
    int y = lds[t];
    int z = (t>=off) ? lds[t-off] : 0;
    __syncthreads();
    lds[t] = y+z;
    __syncthreads();
  }
  int excl = (t>0) ? lds[t-1] : 0;
  if(base+0 < NN) rowstart[base+1] = excl + v0;
  if(base+1 < NN) rowstart[base+2] = excl + s1;
  if(base+2 < NN) rowstart[base+3] = excl + s2;
  if(base+3 < NN) rowstart[base+4] = excl + s3;
  if(t == 255) bsums[b] = lds[255];
}

__global__ void k_scan2(int* __restrict__ bsums, int nb){
  __shared__ int lds[256];
  int t = threadIdx.x;
  int v = (t < nb) ? bsums[t] : 0;
  lds[t] = v;
  __syncthreads();
  for(int off=1; off<256; off<<=1){
    int y = lds[t];
    int z = (t>=off) ? lds[t-off] : 0;
    __syncthreads();
    lds[t] = y+z;
    __syncthreads();
  }
  int excl = (t>0) ? lds[t-1] : 0;
  if(t < nb) bsums[t] = excl;
}

__global__ __launch_bounds__(256) void k_scan3(int* __restrict__ rowstart, const int* __restrict__ bsums){
  int b = blockIdx.x, t = threadIdx.x;
  int add = bsums[b];
  int base = b*1024 + t*4;
  #pragma unroll
  for(int j=0;j<4;j++)
    if(base+j < NN) rowstart[base+j+1] += add;
  if(b==0 && t==0) rowstart[0] = 0;
}

__global__ __launch_bounds__(256) void k_dinv(const int* __restrict__ counts, float* __restrict__ dinv){
  int n = blockIdx.x*256 + threadIdx.x;
  if(n < NN) dinv[n] = rsqrtf((float)(counts[n] + 1));  // deg = indeg + self loop
}

__global__ __launch_bounds__(256) void k_scatter(const int* __restrict__ ei, const int* __restrict__ rowstart,
                                                 int* __restrict__ cursor, int* __restrict__ srcs){
  int e = blockIdx.x*256 + threadIdx.x;
  if(e < NE){
    int d = ei[NE + e];
    int pos = rowstart[d] + atomicAdd(&cursor[d], 1);
    srcs[pos] = ei[e];
  }
}

// batch is sorted -> contiguous per-graph node ranges
__global__ __launch_bounds__(256) void k_granges(const int* __restrict__ batch, int* __restrict__ gstart){
  int n = blockIdx.x*256 + threadIdx.x;
  if(n >= NN) return;
  int b = batch[n];
  if(n == 0){
    for(int g=0; g<=b; g++) gstart[g] = 0;
    int last = batch[NN-1];
    for(int g=last+1; g<=NG; g++) gstart[g] = NN;
  } else {
    int bp = batch[n-1];
    for(int g=bp+1; g<=b; g++) gstart[g] = n;
  }
}

// ---------------- weight transpose+bf16: wT[layer][h][k] = bf16(w[k][h]) ----------------
__global__ __launch_bounds__(256) void k_prepw(const float* __restrict__ w1, const float* __restrict__ w2,
                                               const float* __restrict__ w3, ushort* __restrict__ wT){
  const float* w = (blockIdx.x == 0) ? w1 : (blockIdx.x == 1) ? w2 : w3;
  ushort* o = wT + blockIdx.x*16384;
  #pragma unroll 4
  for(int i=0;i<64;i++){
    int e = i*256 + threadIdx.x;
    int k = e>>7, h = e&127;
    o[h*128 + k] = f2b(w[e]);
  }
}

// ---------------- MFMA GEMM: g[node][h] = bf16( dinv[node] * (norm_relu(in[node]) @ w)[h] ) ----
// NORM=0: raw input (layer 1). NORM=1: fused GraphNorm+ReLU on load using am/rs tables.
// A-frag:  lane l holds A[row=l&15][k=(l>>4)*8+j]   (16B contiguous in LDS, pitch 272B -> 2-way)
// B-frag:  lane l holds W[k=(l>>4)*8+j][col=l&15]   (from wT[col][k], 16B contiguous, L1-hot)
// C/D:     col=l&15, row=(l>>4)*4+reg               (m89/m91-verified layout)
template<int NORM>
__global__ __launch_bounds__(256)
void k_gemm(const float* __restrict__ in, const ushort* __restrict__ wT,
            ushort* __restrict__ g, const float* __restrict__ dinv,
            const int* __restrict__ batch,
            const float* __restrict__ gw, const float* __restrict__ gb,
            const float* __restrict__ am_tab, const float* __restrict__ rs_tab)
{
  __shared__ ushort lds_a[128*136];
  __shared__ float sdinv[128];
  const int t = threadIdx.x;
  const int row0 = blockIdx.x * 128;

  { // stage A tile: fp32 -> (norm+relu) -> bf16
    const int l = t & 31;          // float4 slot (f0 = 4*l)
    const int rr = t >> 5;         // 0..7
    if(t < 128){
      int node = row0 + t;
      sdinv[t] = (node < NN) ? dinv[node] : 0.f;
    }
    float4 gwv, gbv;
    if(NORM){ gwv = ((const float4*)gw)[l]; gbv = ((const float4*)gb)[l]; }
    #pragma unroll 4
    for(int rb = 0; rb < 16; rb++){
      int r = rb*8 + rr;
      int node = row0 + r;
      float4 v = make_float4(0.f,0.f,0.f,0.f);
      if(node < NN){
        v = ((const float4*)in)[(size_t)node*32 + l];
        if(NORM){
          int gg = batch[node];
          float4 am = ((const float4*)am_tab)[gg*32 + l];
          float4 rs = ((const float4*)rs_tab)[gg*32 + l];
          v.x = fmaxf(gwv.x*(v.x-am.x)*rs.x + gbv.x, 0.f);
          v.y = fmaxf(gwv.y*(v.y-am.y)*rs.y + gbv.y, 0.f);
          v.z = fmaxf(gwv.z*(v.z-am.z)*rs.z + gbv.z, 0.f);
          v.w = fmaxf(gwv.w*(v.w-am.w)*rs.w + gbv.w, 0.f);
        }
      }
      ushort4 b4;
      b4.x = f2b(v.x); b4.y = f2b(v.y); b4.z = f2b(v.z); b4.w = f2b(v.w);
      *(ushort4*)(lds_a + r*136 + l*4) = b4;
    }
  }
  __syncthreads();

  const int wv = t >> 6;          // wave 0..3 -> cols wv*32 .. wv*32+31
  const int l  = t & 63;
  const int lc = l & 15, lk = l >> 4;

  short8 bfrag[2][4];
  #pragma unroll
  for(int tt=0; tt<2; tt++){
    int col = wv*32 + tt*16 + lc;
    #pragma unroll
    for(int s=0; s<4; s++)
      bfrag[tt][s] = *(const short8*)(wT + col*128 + s*32 + lk*8);
  }

  f32x4 acc[8][2];
  #pragma unroll
  for(int m=0;m<8;m++){ acc[m][0] = (f32x4)0.f; acc[m][1] = (f32x4)0.f; }

  #pragma unroll
  for(int m=0; m<8; m++){
    const ushort* ap = lds_a + (m*16 + lc)*136 + lk*8;
    #pragma unroll
    for(int s=0; s<4; s++){
      short8 a = *(const short8*)(ap + s*32);
      acc[m][0] = __builtin_amdgcn_mfma_f32_16x16x32_bf16(a, bfrag[0][s], acc[m][0], 0, 0, 0);
      acc[m][1] = __builtin_amdgcn_mfma_f32_16x16x32_bf16(a, bfrag[1][s], acc[m][1], 0, 0, 0);
    }
  }

  #pragma unroll
  for(int m=0; m<8; m++){
    #pragma unroll
    for(int tt=0; tt<2; tt++){
      int colg = wv*32 + tt*16 + lc;
      #pragma unroll
      for(int r=0; r<4; r++){
        int row = m*16 + lk*4 + r;
        int node = row0 + row;
        if(node < NN)
          g[(size_t)node*128 + colg] = f2b(acc[m][tt][r] * sdinv[row]);
      }
    }
  }
}

// ---------------- aggregation over dst-sorted edges (bf16 gather, fp32 accum) ----------------
// out[n] = dinv[n]*(sum_{e->n} g[src] + g[n]) + bias
__global__ __launch_bounds__(256)
void k_agg(const ushort* __restrict__ g, const int* __restrict__ rowstart,
           const int* __restrict__ srcs, const float* __restrict__ dinv,
           const float* __restrict__ bias, float* __restrict__ outp)
{
  int lane = threadIdx.x & 31;                // 32 lanes * 4 bf16 = 128 features
  int node = blockIdx.x*8 + (threadIdx.x >> 5);
  if(node >= NN) return;
  int e0 = rowstart[node], e1 = rowstart[node+1];
  float ax=0.f, ay=0.f, az=0.f, aw=0.f;
  const ushort4* gp = (const ushort4*)g;      // index: node*32 + lane
  int e = e0;
  for(; e+1 < e1; e += 2){
    int s0 = srcs[e], s1 = srcs[e+1];
    ushort4 va = gp[(size_t)s0*32 + lane];
    ushort4 vb = gp[(size_t)s1*32 + lane];
    ax += b2f(va.x) + b2f(vb.x); ay += b2f(va.y) + b2f(vb.y);
    az += b2f(va.z) + b2f(vb.z); aw += b2f(va.w) + b2f(vb.w);
  }
  if(e < e1){
    ushort4 va = gp[(size_t)srcs[e]*32 + lane];
    ax += b2f(va.x); ay += b2f(va.y); az += b2f(va.z); aw += b2f(va.w);
  }
  ushort4 vs = gp[(size_t)node*32 + lane];
  float dv = dinv[node];
  float4 bv = ((const float4*)bias)[lane];
  float4 o = make_float4(dv*(ax+b2f(vs.x))+bv.x, dv*(ay+b2f(vs.y))+bv.y,
                         dv*(az+b2f(vs.z))+bv.z, dv*(aw+b2f(vs.w))+bv.w);
  ((float4*)outp)[(size_t)node*32 + lane] = o;
}

// ---------------- per-graph moments (one pass: sum x, sum x^2) ----------------
#define STAT_CH 8
__global__ __launch_bounds__(128)
void k_stats(const float* __restrict__ x, const int* __restrict__ gstart,
             float* __restrict__ S1, float* __restrict__ S2)
{
  int g = blockIdx.x, ch = blockIdx.y, f = threadIdx.x;
  int s = gstart[g], e = gstart[g+1];
  int len = e - s;
  int i0 = s + (int)((long long)len * ch / STAT_CH);
  int i1 = s + (int)((long long)len * (ch+1) / STAT_CH);
  float a1 = 0.f, a2 = 0.f;
  for(int n=i0; n<i1; n++){
    float v = x[(size_t)n*128 + f];
    a1 += v; a2 += v*v;
  }
  if(i1 > i0){
    atomicAdd(&S1[g*128+f], a1);
    atomicAdd(&S2[g*128+f], a2);
  }
}

// var = E[x^2] - (2a - a^2) m^2 ;  tables: am = a*m, rs = rsqrt(var+eps)
__global__ __launch_bounds__(256)
void k_finalize(const float* __restrict__ S1, const float* __restrict__ S2,
                const int* __restrict__ gstart, const float* __restrict__ ga,
                float* __restrict__ am_tab, float* __restrict__ rs_tab)
{
  int i = blockIdx.x*256 + threadIdx.x;
  if(i >= NG*HD) return;
  int g = i >> 7, f = i & 127;
  int len = gstart[g+1] - gstart[g];
  float cnt = (float)(len > 0 ? len : 1);
  float inv = 1.f/cnt;
  float m = S1[i]*inv, ex2 = S2[i]*inv;
  float a = ga[f];
  float var = ex2 - (2.f*a - a*a)*m*m;
  am_tab[i] = a*m;
  rs_tab[i] = rsqrtf(var + EPSV);
}

// ---------------- pooled[g][f] = sum_n relu(norm3(x[n][f]))  (divide by cnt in head) ----------
__global__ __launch_bounds__(128)
void k_pool(const float* __restrict__ x, const int* __restrict__ gstart,
            const float* __restrict__ gw, const float* __restrict__ gb,
            const float* __restrict__ am_tab, const float* __restrict__ rs_tab,
            float* __restrict__ pooled)
{
  int g = blockIdx.x, ch = blockIdx.y, f = threadIdx.x;
  int s = gstart[g], e = gstart[g+1];
  int len = e - s;
  int i0 = s + (int)((long long)len * ch / STAT_CH);
  int i1 = s + (int)((long long)len * (ch+1) / STAT_CH);
  float wv = gw[f], bv = gb[f];
  float am = am_tab[g*128+f], rs = rs_tab[g*128+f];
  float a1 = 0.f;
  for(int n=i0; n<i1; n++){
    float v = x[(size_t)n*128 + f];
    v = wv*(v-am)*rs + bv;
    a1 += fmaxf(v, 0.f);
  }
  if(i1 > i0) atomicAdd(&pooled[g*128+f], a1);
}

// ---------------- head: logits = pooled/cnt @ lw + lb, log_softmax ----------------
__global__ __launch_bounds__(64)
void k_head(const float* __restrict__ pooled, const int* __restrict__ gstart,
            const float* __restrict__ lw, const float* __restrict__ lb,
            float* __restrict__ out)
{
  int g = blockIdx.x, t = threadIdx.x;
  __shared__ float lg[NC];
  __shared__ float lse_s;
  int len = gstart[g+1] - gstart[g];
  float inv = 1.f/(float)(len > 0 ? len : 1);
  if(t < NC){
    float acc = lb[t];
    for(int f=0; f<128; f++) acc += pooled[g*128+f]*inv*lw[f*NC + t];
    lg[t] = acc;
  }
  __syncthreads();
  if(t == 0){
    float mx = -1e30f;
    for(int c=0;c<NC;c++) mx = fmaxf(mx, lg[c]);
    float sm = 0.f;
    for(int c=0;c<NC;c++) sm += expf(lg[c]-mx);
    lse_s = mx + logf(sm);
  }
  __syncthreads();
  if(t < NC) out[g*NC + t] = lg[t] - lse_s;
}

// ---------------- launch ----------------
extern "C" void kernel_launch(void* const* d_in, const int* in_sizes, int n_in,
                              void* d_out, int out_size, void* d_ws, size_t ws_size,
                              hipStream_t stream)
{
  const float* x    = (const float*)d_in[0];
  const int*   ei   = (const int*)d_in[1];
  const int*   batch= (const int*)d_in[2];
  const float* w1   = (const float*)d_in[3];
  const float* b1   = (const float*)d_in[4];
  const float* w2   = (const float*)d_in[5];
  const float* b2   = (const float*)d_in[6];
  const float* w3   = (const float*)d_in[7];
  const float* b3   = (const float*)d_in[8];
  const float* g1w  = (const float*)d_in[9];
  const float* g1b  = (const float*)d_in[10];
  const float* g1a  = (const float*)d_in[11];
  const float* g2w  = (const float*)d_in[12];
  const float* g2b  = (const float*)d_in[13];
  const float* g2a  = (const float*)d_in[14];
  const float* g3w  = (const float*)d_in[15];
  const float* g3b  = (const float*)d_in[16];
  const float* g3a  = (const float*)d_in[17];
  const float* lw   = (const float*)d_in[18];
  const float* lb   = (const float*)d_in[19];
  float* out = (float*)d_out;

  char* p = (char*)d_ws;
  auto take = [&](size_t nbytes){ char* q = p; p += (nbytes + 255) & ~(size_t)255; return q; };
  ushort* gbuf    = (ushort*)take((size_t)NN*HD*2);
  float* bufB     = (float*)take((size_t)NN*HD*4);
  ushort* wT      = (ushort*)take((size_t)3*HD*HD*2);
  int*   counts   = (int*)  take((size_t)NN*4);
  int*   rowstart = (int*)  take((size_t)(NN+1)*4);
  int*   cursor   = (int*)  take((size_t)NN*4);
  int*   srcs     = (int*)  take((size_t)NE*4);
  float* dinv     = (float*)take((size_t)NN*4);
  int*   gstart   = (int*)  take((size_t)(NG+1)*4);
  float* S1       = (float*)take((size_t)NG*HD*4);
  float* S2       = (float*)take((size_t)NG*HD*4);
  float* am_tab   = (float*)take((size_t)NG*HD*4);
  float* rs_tab   = (float*)take((size_t)NG*HD*4);
  float* pooled   = (float*)take((size_t)NG*HD*4);
  int*   bsums    = (int*)  take((size_t)512*4);
  if((size_t)(p - (char*)d_ws) > ws_size) return;  // workspace too small: fail visibly

  hipMemsetAsync(counts, 0, (size_t)NN*4, stream);
  hipMemsetAsync(cursor, 0, (size_t)NN*4, stream);

  const int NB = (NN + 1023)/1024;   // 98
  k_count  <<<(NE+255)/256, 256, 0, stream>>>(ei, counts);
  k_scan1  <<<NB, 256, 0, stream>>>(counts, rowstart, bsums);
  k_scan2  <<<1, 256, 0, stream>>>(bsums, NB);
  k_scan3  <<<NB, 256, 0, stream>>>(rowstart, bsums);
  k_dinv   <<<(NN+255)/256, 256, 0, stream>>>(counts, dinv);
  k_scatter<<<(NE+255)/256, 256, 0, stream>>>(ei, rowstart, cursor, srcs);
  k_granges<<<(NN+255)/256, 256, 0, stream>>>(batch, gstart);
  k_prepw  <<<3, 256, 0, stream>>>(w1, w2, w3, wT);

  const int GB = (NN + 127)/128;     // 782

  // ---- layer 1 ----
  k_gemm<0><<<GB, 256, 0, stream>>>(x, wT, gbuf, dinv, batch, nullptr, nullptr, nullptr, nullptr);
  k_agg<<<(NN+7)/8, 256, 0, stream>>>(gbuf, rowstart, srcs, dinv, b1, bufB);
  hipMemsetAsync(S1, 0, (size_t)NG*HD*4, stream);
  hipMemsetAsync(S2, 0, (size_t)NG*HD*4, stream);
  k_stats<<<dim3(NG, STAT_CH), 128, 0, stream>>>(bufB, gstart, S1, S2);
  k_finalize<<<(NG*HD+255)/256, 256, 0, stream>>>(S1, S2, gstart, g1a, am_tab, rs_tab);

  // ---- layer 2 ----
  k_gemm<1><<<GB, 256, 0, stream>>>(bufB, wT + 16384, gbuf, dinv, batch, g1w, g1b, am_tab, rs_tab);
  k_agg<<<(NN+7)/8, 256, 0, stream>>>(gbuf, rowstart, srcs, dinv, b2, bufB);
  hipMemsetAsync(S1, 0, (size_t)NG*HD*4, stream);
  hipMemsetAsync(S2, 0, (size_t)NG*HD*4, stream);
  k_stats<<<dim3(NG, STAT_CH), 128, 0, stream>>>(bufB, gstart, S1, S2);
  k_finalize<<<(NG*HD+255)/256, 256, 0, stream>>>(S1, S2, gstart, g2a, am_tab, rs_tab);

  // ---- layer 3 ----
  k_gemm<1><<<GB, 256, 0, stream>>>(bufB, wT + 32768, gbuf, dinv, batch, g2w, g2b, am_tab, rs_tab);
  k_agg<<<(NN+7)/8, 256, 0, stream>>>(gbuf, rowstart, srcs, dinv, b3, bufB);
  hipMemsetAsync(S1, 0, (size_t)NG*HD*4, stream);
  hipMemsetAsync(S2, 0, (size_t)NG*HD*4, stream);
  k_stats<<<dim3(NG, STAT_CH), 128, 0, stream>>>(bufB, gstart, S1, S2);
  k_finalize<<<(NG*HD+255)/256, 256, 0, stream>>>(S1, S2, gstart, g3a, am_tab, rs_tab);

  // ---- pool + head ----
  hipMemsetAsync(pooled, 0, (size_t)NG*HD*4, stream);
  k_pool<<<dim3(NG, STAT_CH), 128, 0, stream>>>(bufB, gstart, g3w, g3b, am_tab, rs_tab, pooled);
  k_head<<<NG, 64, 0, stream>>>(pooled, gstart, lw, lb, out);
}

// Round 3
// 487.296 us; speedup vs baseline: 2.0380x; 1.3870x over previous
//
#include <hip/hip_runtime.h>

#define NN 100000
#define NE 1600000
#define HD 128
#define NG 128
#define NC 10
#define EPSV 1e-5f

#define BSH 9                      // 512 dst nodes per bucket
#define NBKT ((NN + 511) >> 9)     // 196
#define BIN_BLOCKS ((NE + 4095) / 4096)  // 391

typedef __attribute__((ext_vector_type(8))) short short8;
typedef __attribute__((ext_vector_type(4))) float f32x4;

__device__ __forceinline__ float b2f(ushort u){ return __uint_as_float(((unsigned)u)<<16); }
__device__ __forceinline__ ushort f2b(float f){
  unsigned u = __float_as_uint(f);
  unsigned r = (u + 0x7FFFu + ((u>>16)&1u)) >> 16;   // RNE
  return (ushort)r;
}

// ---------------- pass 0: global bucket histogram ----------------
__global__ __launch_bounds__(256) void k_bhist(const int* __restrict__ ei, int* __restrict__ gbhist){
  __shared__ int h[NBKT];
  int t = threadIdx.x;
  if(t < NBKT) h[t] = 0;
  __syncthreads();
  int base = blockIdx.x*4096;
  #pragma unroll
  for(int i=0;i<16;i++){
    int e = base + i*256 + t;
    if(e < NE) atomicAdd(&h[ei[NE + e] >> BSH], 1);
  }
  __syncthreads();
  if(t < NBKT && h[t]) atomicAdd(&gbhist[t], h[t]);
}

__global__ void k_bscan(const int* __restrict__ gbhist, int* __restrict__ bucket_base,
                        int* __restrict__ bucket_cursor, int* __restrict__ rowstart){
  __shared__ int lds[256];
  int t = threadIdx.x;
  int v = (t < NBKT) ? gbhist[t] : 0;
  lds[t] = v; __syncthreads();
  for(int off=1; off<256; off<<=1){
    int y = lds[t]; int z = (t>=off)?lds[t-off]:0;
    __syncthreads(); lds[t] = y+z; __syncthreads();
  }
  int excl = (t>0)?lds[t-1]:0;
  if(t < NBKT){ bucket_base[t] = excl; bucket_cursor[t] = excl; }
  if(t == 0){ bucket_base[NBKT] = NE; rowstart[NN] = NE; }
}

// ---------------- pass 1: bin edges by dst bucket (LDS-staged, contiguous writes) ----------
__global__ __launch_bounds__(256) void k_bin(const int* __restrict__ ei, int* __restrict__ bucket_cursor,
                                             unsigned long long* __restrict__ ebuf){
  __shared__ unsigned long long eb[4096];
  __shared__ int hist[NBKT], lstart[NBKT], lcur[NBKT], rbase[NBKT];
  __shared__ int scanbuf[256];
  int t = threadIdx.x;
  if(t < NBKT) hist[t] = 0;
  __syncthreads();
  int base = blockIdx.x*4096;
  int nv = NE - base; if(nv > 4096) nv = 4096;
  int se[16], de[16];
  #pragma unroll
  for(int i=0;i<16;i++){
    int e = base + i*256 + t;
    if(e < NE){ se[i] = ei[e]; de[i] = ei[NE + e]; atomicAdd(&hist[de[i] >> BSH], 1); }
  }
  __syncthreads();
  int v = (t < NBKT) ? hist[t] : 0;
  scanbuf[t] = v; __syncthreads();
  for(int off=1; off<256; off<<=1){
    int y = scanbuf[t]; int z = (t>=off)?scanbuf[t-off]:0;
    __syncthreads(); scanbuf[t] = y+z; __syncthreads();
  }
  if(t < NBKT){
    int excl = (t>0)?scanbuf[t-1]:0;
    lstart[t] = excl; lcur[t] = excl;
    if(hist[t]) rbase[t] = atomicAdd(&bucket_cursor[t], hist[t]);
  }
  __syncthreads();
  #pragma unroll
  for(int i=0;i<16;i++){
    int e = base + i*256 + t;
    if(e < NE){
      int b = de[i] >> BSH;
      int idx = atomicAdd(&lcur[b], 1);
      eb[idx] = ((unsigned long long)(unsigned)de[i] << 32) | (unsigned)se[i];
    }
  }
  __syncthreads();
  #pragma unroll
  for(int i=0;i<16;i++){
    int slot = i*256 + t;
    if(slot < nv){
      unsigned long long v8 = eb[slot];
      int b = (int)(v8 >> 32) >> BSH;
      ebuf[rbase[b] + (slot - lstart[b])] = v8;
    }
  }
}

// ---------------- pass 2: per-bucket counting sort (XCD-local window) + rowstart + dinv ------
__global__ __launch_bounds__(256) void k_sort(const unsigned long long* __restrict__ ebuf,
                                              const int* __restrict__ bucket_base,
                                              int* __restrict__ srcs, int* __restrict__ rowstart,
                                              float* __restrict__ dinv){
  __shared__ int hist[512], cur[512];
  __shared__ int scanbuf[256];
  int b = blockIdx.x, t = threadIdx.x;
  int e0 = bucket_base[b], e1 = bucket_base[b+1];
  hist[t] = 0; hist[t+256] = 0;
  __syncthreads();
  for(int i = e0 + t; i < e1; i += 256){
    int dl = (int)(ebuf[i] >> 32) - (b << BSH);
    atomicAdd(&hist[dl], 1);
  }
  __syncthreads();
  int s0 = hist[2*t], s1 = hist[2*t+1];
  scanbuf[t] = s0 + s1; __syncthreads();
  for(int off=1; off<256; off<<=1){
    int y = scanbuf[t]; int z = (t>=off)?scanbuf[t-off]:0;
    __syncthreads(); scanbuf[t] = y+z; __syncthreads();
  }
  int excl = (t>0)?scanbuf[t-1]:0;
  cur[2*t] = excl; cur[2*t+1] = excl + s0;
  int d0 = (b << BSH) + 2*t, d1 = d0 + 1;
  if(d0 < NN){ rowstart[d0] = e0 + excl;      dinv[d0] = rsqrtf((float)(s0 + 1)); }
  if(d1 < NN){ rowstart[d1] = e0 + excl + s0; dinv[d1] = rsqrtf((float)(s1 + 1)); }
  __syncthreads();
  for(int i = e0 + t; i < e1; i += 256){
    unsigned long long v8 = ebuf[i];
    int dl = (int)(v8 >> 32) - (b << BSH);
    int pos = e0 + atomicAdd(&cur[dl], 1);
    srcs[pos] = (int)(unsigned)v8;
  }
}

// batch is sorted -> contiguous per-graph node ranges
__global__ __launch_bounds__(256) void k_granges(const int* __restrict__ batch, int* __restrict__ gstart){
  int n = blockIdx.x*256 + threadIdx.x;
  if(n >= NN) return;
  int b = batch[n];
  if(n == 0){
    for(int g=0; g<=b; g++) gstart[g] = 0;
    int last = batch[NN-1];
    for(int g=last+1; g<=NG; g++) gstart[g] = NN;
  } else {
    int bp = batch[n-1];
    for(int g=bp+1; g<=b; g++) gstart[g] = n;
  }
}

// ---------------- weight transpose+bf16: wT[layer][h][k] = bf16(w[k][h]) ----------------
__global__ __launch_bounds__(256) void k_prepw(const float* __restrict__ w1, const float* __restrict__ w2,
                                               const float* __restrict__ w3, ushort* __restrict__ wT){
  const float* w = (blockIdx.x == 0) ? w1 : (blockIdx.x == 1) ? w2 : w3;
  ushort* o = wT + blockIdx.x*16384;
  #pragma unroll 4
  for(int i=0;i<64;i++){
    int e = i*256 + threadIdx.x;
    int k = e>>7, h = e&127;
    o[h*128 + k] = f2b(w[e]);
  }
}

// ---------------- MFMA GEMM: g[node][h] = bf16( dinv[node] * (norm_relu(in[node]) @ w)[h] ) ----
template<int NORM>
__global__ __launch_bounds__(256)
void k_gemm(const float* __restrict__ in, const ushort* __restrict__ wT,
            ushort* __restrict__ g, const float* __restrict__ dinv,
            const int* __restrict__ batch,
            const float* __restrict__ gw, const float* __restrict__ gb,
            const float* __restrict__ am_tab, const float* __restrict__ rs_tab)
{
  __shared__ ushort lds_a[128*136];
  __shared__ float sdinv[128];
  const int t = threadIdx.x;
  const int row0 = blockIdx.x * 128;

  { // stage A tile: fp32 -> (norm+relu) -> bf16
    const int l = t & 31;          // float4 slot (f0 = 4*l)
    const int rr = t >> 5;         // 0..7
    if(t < 128){
      int node = row0 + t;
      sdinv[t] = (node < NN) ? dinv[node] : 0.f;
    }
    float4 gwv, gbv;
    if(NORM){ gwv = ((const float4*)gw)[l]; gbv = ((const float4*)gb)[l]; }
    #pragma unroll 4
    for(int rb = 0; rb < 16; rb++){
      int r = rb*8 + rr;
      int node = row0 + r;
      float4 v = make_float4(0.f,0.f,0.f,0.f);
      if(node < NN){
        v = ((const float4*)in)[(size_t)node*32 + l];
        if(NORM){
          int gg = batch[node];
          float4 am = ((const float4*)am_tab)[gg*32 + l];
          float4 rs = ((const float4*)rs_tab)[gg*32 + l];
          v.x = fmaxf(gwv.x*(v.x-am.x)*rs.x + gbv.x, 0.f);
          v.y = fmaxf(gwv.y*(v.y-am.y)*rs.y + gbv.y, 0.f);
          v.z = fmaxf(gwv.z*(v.z-am.z)*rs.z + gbv.z, 0.f);
          v.w = fmaxf(gwv.w*(v.w-am.w)*rs.w + gbv.w, 0.f);
        }
      }
      ushort4 b4;
      b4.x = f2b(v.x); b4.y = f2b(v.y); b4.z = f2b(v.z); b4.w = f2b(v.w);
      *(ushort4*)(lds_a + r*136 + l*4) = b4;
    }
  }
  __syncthreads();

  const int wv = t >> 6;          // wave 0..3 -> cols wv*32 .. wv*32+31
  const int l  = t & 63;
  const int lc = l & 15, lk = l >> 4;

  short8 bfrag[2][4];
  #pragma unroll
  for(int tt=0; tt<2; tt++){
    int col = wv*32 + tt*16 + lc;
    #pragma unroll
    for(int s=0; s<4; s++)
      bfrag[tt][s] = *(const short8*)(wT + col*128 + s*32 + lk*8);
  }

  f32x4 acc[8][2];
  #pragma unroll
  for(int m=0;m<8;m++){ acc[m][0] = (f32x4)0.f; acc[m][1] = (f32x4)0.f; }

  #pragma unroll
  for(int m=0; m<8; m++){
    const ushort* ap = lds_a + (m*16 + lc)*136 + lk*8;
    #pragma unroll
    for(int s=0; s<4; s++){
      short8 a = *(const short8*)(ap + s*32);
      acc[m][0] = __builtin_amdgcn_mfma_f32_16x16x32_bf16(a, bfrag[0][s], acc[m][0], 0, 0, 0);
      acc[m][1] = __builtin_amdgcn_mfma_f32_16x16x32_bf16(a, bfrag[1][s], acc[m][1], 0, 0, 0);
    }
  }

  #pragma unroll
  for(int m=0; m<8; m++){
    #pragma unroll
    for(int tt=0; tt<2; tt++){
      int colg = wv*32 + tt*16 + lc;
      #pragma unroll
      for(int r=0; r<4; r++){
        int row = m*16 + lk*4 + r;
        int node = row0 + row;
        if(node < NN)
          g[(size_t)node*128 + colg] = f2b(acc[m][tt][r] * sdinv[row]);
      }
    }
  }
}

// ---------------- aggregation over dst-sorted edges (bf16 gather, fp32 accum) ----------------
__global__ __launch_bounds__(256)
void k_agg(const ushort* __restrict__ g, const int* __restrict__ rowstart,
           const int* __restrict__ srcs, const float* __restrict__ dinv,
           const float* __restrict__ bias, float* __restrict__ outp)
{
  int lane = threadIdx.x & 31;                // 32 lanes * 4 bf16 = 128 features
  int node = blockIdx.x*8 + (threadIdx.x >> 5);
  if(node >= NN) return;
  int e0 = rowstart[node], e1 = rowstart[node+1];
  float ax=0.f, ay=0.f, az=0.f, aw=0.f;
  float bx=0.f, by=0.f, bz=0.f, bw=0.f;
  const ushort4* gp = (const ushort4*)g;      // index: node*32 + lane
  int e = e0;
  for(; e+3 < e1; e += 4){
    int s0 = srcs[e], s1 = srcs[e+1], s2 = srcs[e+2], s3 = srcs[e+3];
    ushort4 va = gp[(size_t)s0*32 + lane];
    ushort4 vb = gp[(size_t)s1*32 + lane];
    ushort4 vc = gp[(size_t)s2*32 + lane];
    ushort4 vd = gp[(size_t)s3*32 + lane];
    ax += b2f(va.x) + b2f(vb.x); ay += b2f(va.y) + b2f(vb.y);
    az += b2f(va.z) + b2f(vb.z); aw += b2f(va.w) + b2f(vb.w);
    bx += b2f(vc.x) + b2f(vd.x); by += b2f(vc.y) + b2f(vd.y);
    bz += b2f(vc.z) + b2f(vd.z); bw += b2f(vc.w) + b2f(vd.w);
  }
  for(; e < e1; e++){
    ushort4 va = gp[(size_t)srcs[e]*32 + lane];
    ax += b2f(va.x); ay += b2f(va.y); az += b2f(va.z); aw += b2f(va.w);
  }
  ax += bx; ay += by; az += bz; aw += bw;
  ushort4 vs = gp[(size_t)node*32 + lane];
  float dv = dinv[node];
  float4 bv = ((const float4*)bias)[lane];
  float4 o = make_float4(dv*(ax+b2f(vs.x))+bv.x, dv*(ay+b2f(vs.y))+bv.y,
                         dv*(az+b2f(vs.z))+bv.z, dv*(aw+b2f(vs.w))+bv.w);
  ((float4*)outp)[(size_t)node*32 + lane] = o;
}

// ---------------- per-graph moments (one pass: sum x, sum x^2) ----------------
#define STAT_CH 8
__global__ __launch_bounds__(128)
void k_stats(const float* __restrict__ x, const int* __restrict__ gstart,
             float* __restrict__ S1, float* __restrict__ S2)
{
  int g = blockIdx.x, ch = blockIdx.y, f = threadIdx.x;
  int s = gstart[g], e = gstart[g+1];
  int len = e - s;
  int i0 = s + (int)((long long)len * ch / STAT_CH);
  int i1 = s + (int)((long long)len * (ch+1) / STAT_CH);
  float a1 = 0.f, a2 = 0.f;
  for(int n=i0; n<i1; n++){
    float v = x[(size_t)n*128 + f];
    a1 += v; a2 += v*v;
  }
  if(i1 > i0){
    atomicAdd(&S1[g*128+f], a1);
    atomicAdd(&S2[g*128+f], a2);
  }
}

// var = E[x^2] - (2a - a^2) m^2 ; tables: am = a*m, rs = rsqrt(var+eps). Self-zeroes S1/S2.
__global__ __launch_bounds__(256)
void k_finalize(float* __restrict__ S1, float* __restrict__ S2,
                const int* __restrict__ gstart, const float* __restrict__ ga,
                float* __restrict__ am_tab, float* __restrict__ rs_tab)
{
  int i = blockIdx.x*256 + threadIdx.x;
  if(i >= NG*HD) return;
  int g = i >> 7, f = i & 127;
  int len = gstart[g+1] - gstart[g];
  float cnt = (float)(len > 0 ? len : 1);
  float inv = 1.f/cnt;
  float m = S1[i]*inv, ex2 = S2[i]*inv;
  float a = ga[f];
  float var = ex2 - (2.f*a - a*a)*m*m;
  am_tab[i] = a*m;
  rs_tab[i] = rsqrtf(var + EPSV);
  S1[i] = 0.f; S2[i] = 0.f;       // ready for next layer's k_stats
}

// ---------------- pooled[g][f] = sum_n relu(norm3(x[n][f]))  (divide by cnt in head) ----------
__global__ __launch_bounds__(128)
void k_pool(const float* __restrict__ x, const int* __restrict__ gstart,
            const float* __restrict__ gw, const float* __restrict__ gb,
            const float* __restrict__ am_tab, const float* __restrict__ rs_tab,
            float* __restrict__ pooled)
{
  int g = blockIdx.x, ch = blockIdx.y, f = threadIdx.x;
  int s = gstart[g], e = gstart[g+1];
  int len = e - s;
  int i0 = s + (int)((long long)len * ch / STAT_CH);
  int i1 = s + (int)((long long)len * (ch+1) / STAT_CH);
  float wv = gw[f], bv = gb[f];
  float am = am_tab[g*128+f], rs = rs_tab[g*128+f];
  float a1 = 0.f;
  for(int n=i0; n<i1; n++){
    float v = x[(size_t)n*128 + f];
    v = wv*(v-am)*rs + bv;
    a1 += fmaxf(v, 0.f);
  }
  if(i1 > i0) atomicAdd(&pooled[g*128+f], a1);
}

// ---------------- head: logits = pooled/cnt @ lw + lb, log_softmax ----------------
__global__ __launch_bounds__(64)
void k_head(const float* __restrict__ pooled, const int* __restrict__ gstart,
            const float* __restrict__ lw, const float* __restrict__ lb,
            float* __restrict__ out)
{
  int g = blockIdx.x, t = threadIdx.x;
  __shared__ float lg[NC];
  __shared__ float lse_s;
  int len = gstart[g+1] - gstart[g];
  float inv = 1.f/(float)(len > 0 ? len : 1);
  if(t < NC){
    float acc = lb[t];
    for(int f=0; f<128; f++) acc += pooled[g*128+f]*inv*lw[f*NC + t];
    lg[t] = acc;
  }
  __syncthreads();
  if(t == 0){
    float mx = -1e30f;
    for(int c=0;c<NC;c++) mx = fmaxf(mx, lg[c]);
    float sm = 0.f;
    for(int c=0;c<NC;c++) sm += expf(lg[c]-mx);
    lse_s = mx + logf(sm);
  }
  __syncthreads();
  if(t < NC) out[g*NC + t] = lg[t] - lse_s;
}

// ---------------- launch ----------------
extern "C" void kernel_launch(void* const* d_in, const int* in_sizes, int n_in,
                              void* d_out, int out_size, void* d_ws, size_t ws_size,
                              hipStream_t stream)
{
  const float* x    = (const float*)d_in[0];
  const int*   ei   = (const int*)d_in[1];
  const int*   batch= (const int*)d_in[2];
  const float* w1   = (const float*)d_in[3];
  const float* b1   = (const float*)d_in[4];
  const float* w2   = (const float*)d_in[5];
  const float* b2   = (const float*)d_in[6];
  const float* w3   = (const float*)d_in[7];
  const float* b3   = (const float*)d_in[8];
  const float* g1w  = (const float*)d_in[9];
  const float* g1b  = (const float*)d_in[10];
  const float* g1a  = (const float*)d_in[11];
  const float* g2w  = (const float*)d_in[12];
  const float* g2b  = (const float*)d_in[13];
  const float* g2a  = (const float*)d_in[14];
  const float* g3w  = (const float*)d_in[15];
  const float* g3b  = (const float*)d_in[16];
  const float* g3a  = (const float*)d_in[17];
  const float* lw   = (const float*)d_in[18];
  const float* lb   = (const float*)d_in[19];
  float* out = (float*)d_out;

  char* p = (char*)d_ws;
  auto take = [&](size_t nbytes){ char* q = p; p += (nbytes + 255) & ~(size_t)255; return q; };
  ushort* gbuf    = (ushort*)take((size_t)NN*HD*2);
  float* bufB     = (float*)take((size_t)NN*HD*4);
  ushort* wT      = (ushort*)take((size_t)3*HD*HD*2);
  unsigned long long* ebuf = (unsigned long long*)take((size_t)NE*8);
  int*   srcs     = (int*)  take((size_t)NE*4);
  int*   rowstart = (int*)  take((size_t)(NN+1)*4);
  float* dinv     = (float*)take((size_t)NN*4);
  int*   gbhist   = (int*)  take((size_t)NBKT*4);
  int*   bucket_base   = (int*)take((size_t)(NBKT+1)*4);
  int*   bucket_cursor = (int*)take((size_t)NBKT*4);
  int*   gstart   = (int*)  take((size_t)(NG+1)*4);
  float* S1       = (float*)take((size_t)NG*HD*4);
  float* S2       = (float*)take((size_t)NG*HD*4);
  float* am_tab   = (float*)take((size_t)NG*HD*4);
  float* rs_tab   = (float*)take((size_t)NG*HD*4);
  float* pooled   = (float*)take((size_t)NG*HD*4);
  if((size_t)(p - (char*)d_ws) > ws_size) return;  // workspace too small: fail visibly

  hipMemsetAsync(gbhist, 0, (size_t)NBKT*4, stream);
  hipMemsetAsync(S1, 0, (size_t)2*NG*HD*4, stream);   // S1+S2 contiguous
  hipMemsetAsync(pooled, 0, (size_t)NG*HD*4, stream);

  k_bhist <<<BIN_BLOCKS, 256, 0, stream>>>(ei, gbhist);
  k_bscan <<<1, 256, 0, stream>>>(gbhist, bucket_base, bucket_cursor, rowstart);
  k_bin   <<<BIN_BLOCKS, 256, 0, stream>>>(ei, bucket_cursor, ebuf);
  k_sort  <<<NBKT, 256, 0, stream>>>(ebuf, bucket_base, srcs, rowstart, dinv);
  k_granges<<<(NN+255)/256, 256, 0, stream>>>(batch, gstart);
  k_prepw <<<3, 256, 0, stream>>>(w1, w2, w3, wT);

  const int GB = (NN + 127)/128;     // 782

  // ---- layer 1 ----
  k_gemm<0><<<GB, 256, 0, stream>>>(x, wT, gbuf, dinv, batch, nullptr, nullptr, nullptr, nullptr);
  k_agg<<<(NN+7)/8, 256, 0, stream>>>(gbuf, rowstart, srcs, dinv, b1, bufB);
  k_stats<<<dim3(NG, STAT_CH), 128, 0, stream>>>(bufB, gstart, S1, S2);
  k_finalize<<<(NG*HD+255)/256, 256, 0, stream>>>(S1, S2, gstart, g1a, am_tab, rs_tab);

  // ---- layer 2 ----
  k_gemm<1><<<GB, 256, 0, stream>>>(bufB, wT + 16384, gbuf, dinv, batch, g1w, g1b, am_tab, rs_tab);
  k_agg<<<(NN+7)/8, 256, 0, stream>>>(gbuf, rowstart, srcs, dinv, b2, bufB);
  k_stats<<<dim3(NG, STAT_CH), 128, 0, stream>>>(bufB, gstart, S1, S2);
  k_finalize<<<(NG*HD+255)/256, 256, 0, stream>>>(S1, S2, gstart, g2a, am_tab, rs_tab);

  // ---- layer 3 ----
  k_gemm<1><<<GB, 256, 0, stream>>>(bufB, wT + 32768, gbuf, dinv, batch, g2w, g2b, am_tab, rs_tab);
  k_agg<<<(NN+7)/8, 256, 0, stream>>>(gbuf, rowstart, srcs, dinv, b3, bufB);
  k_stats<<<dim3(NG, STAT_CH), 128, 0, stream>>>(bufB, gstart, S1, S2);
  k_finalize<<<(NG*HD+255)/256, 256, 0, stream>>>(S1, S2, gstart, g3a, am_tab, rs_tab);

  // ---- pool + head ----
  k_pool<<<dim3(NG, STAT_CH), 128, 0, stream>>>(bufB, gstart, g3w, g3b, am_tab, rs_tab, pooled);
  k_head<<<NG, 64, 0, stream>>>(pooled, gstart, lw, lb, out);
}